// Round 3
// baseline (13541.722 us; speedup 1.0000x reference)
//
#include <hip/hip_runtime.h>
#include <hip/hip_bf16.h>
#include <math.h>

typedef short s16x8 __attribute__((ext_vector_type(8)));   // 8 bf16 payload (guide-verified frag type)
typedef float f32x4 __attribute__((ext_vector_type(4)));
typedef unsigned short u16;

#define MFMA16(a,b,c) __builtin_amdgcn_mfma_f32_16x16x32_bf16((a),(b),(c),0,0,0)

// Problem dims: IN = HID = MEM = 1024, T = 512, B = 64
static constexpr long SLOT      = 64l * 1024;        // B*MEM elems per timestep
static constexpr long FINAL_OFF = 512l * 64 * 1024;  // offset of m_final in d_out

// ws layout (u16 element offsets)
static constexpr long OFF_WXH = 0;
static constexpr long OFF_WMH = 1048576;
static constexpr long OFF_WHM = 2l * 1048576;
static constexpr long OFF_WMM = 3l * 1048576;
static constexpr long OFF_M   = 4l * 1048576;            // m state, bf16 [64][1024]
static constexpr long OFF_H   = 4l * 1048576 + 65536;    // h buffer, bf16 [64][1024]
static constexpr long FLAGS_BYTE = (4l * 1048576 + 2 * 65536) * 2;  // 256 ints

__device__ __forceinline__ u16 f2bf(float f) {
  union { float f; unsigned u; } v; v.f = f;
  unsigned r = v.u + 0x7FFFu + ((v.u >> 16) & 1u);   // round-to-nearest-even
  return (u16)(r >> 16);
}

// ---------------------------------------------------------------------------
// init: cast weights + m_prev to bf16 into ws, zero barrier flags
// ---------------------------------------------------------------------------
__global__ void init_kernel(const float* __restrict__ Wxh, const float* __restrict__ Wmh,
                            const float* __restrict__ Whm, const float* __restrict__ Wmm,
                            const float* __restrict__ mprev,
                            u16* __restrict__ ws, int* __restrict__ flags) {
  long tid  = (long)blockIdx.x * blockDim.x + threadIdx.x;
  long nthr = (long)gridDim.x * blockDim.x;
  const long NV = (4l * 1048576 + 65536) / 4;   // float4 groups
  for (long i = tid; i < NV; i += nthr) {
    long e = i * 4;
    const float* src; long rel;
    if      (e < 1048576)      { src = Wxh;   rel = e; }
    else if (e < 2l * 1048576) { src = Wmh;   rel = e - 1048576; }
    else if (e < 3l * 1048576) { src = Whm;   rel = e - 2l * 1048576; }
    else if (e < 4l * 1048576) { src = Wmm;   rel = e - 3l * 1048576; }
    else                       { src = mprev; rel = e - 4l * 1048576; }
    float4 v = *(const float4*)(src + rel);
    ushort4 o;
    o.x = f2bf(v.x); o.y = f2bf(v.y); o.z = f2bf(v.z); o.w = f2bf(v.w);
    *(ushort4*)(ws + e) = o;
  }
  if (tid < 256) flags[tid] = 0;
}

// ---------------------------------------------------------------------------
// xW = x @ Wxh^T + bh  -> written into d_out[0 .. T*B*1024). Slot t is consumed
// by scan phase 1 of step t (same thread) before phase 2 overwrites it with m_t.
// 128x128 tile, BK=32, 4 waves (2x2), bf16 MFMA 16x16x32.
// ---------------------------------------------------------------------------
__global__ __launch_bounds__(256) void gemm_xw(const float* __restrict__ X,
                                               const u16* __restrict__ Wb,
                                               const float* __restrict__ bh,
                                               float* __restrict__ C) {
  __shared__ __align__(16) u16 As[128 * 40];   // padded stride 40 (2-way max on reads)
  __shared__ __align__(16) u16 Bs[128 * 32];   // linear (global_load_lds destination)
  const int m0 = (blockIdx.x >> 3) * 128;
  const int n0 = (blockIdx.x & 7) * 128;
  const int t = threadIdx.x, l = t & 63, w = t >> 6;
  const int wr = w >> 1, wc = w & 1;
  const int r15 = l & 15, hi = l >> 4;
  f32x4 acc[4][4] = {};

  for (int k0 = 0; k0 < 1024; k0 += 32) {
    // stage A (fp32 -> bf16, reg-staged), 128x32
#pragma unroll
    for (int r = 0; r < 4; ++r) {
      int idx = r * 256 + t;
      int row = idx >> 3, c4 = idx & 7;
      float4 v = *(const float4*)(X + (long)(m0 + row) * 1024 + k0 + c4 * 4);
      ushort4 o;
      o.x = f2bf(v.x); o.y = f2bf(v.y); o.z = f2bf(v.z); o.w = f2bf(v.w);
      *(ushort4*)(As + row * 40 + c4 * 4) = o;
    }
    // stage B via global_load_lds (16B/lane); source pre-swizzled so LDS slot
    // (row, kg) holds source granule kg ^ ((row>>1)&3)  (both-sides swizzle, G21)
#pragma unroll
    for (int i = 0; i < 2; ++i) {
      int g = (w * 2 + i) * 64 + l;
      int row = g >> 2;
      int kgs = (g & 3) ^ ((row >> 1) & 3);
      const u16* src = Wb + (long)(n0 + row) * 1024 + k0 + kgs * 8;
      __builtin_amdgcn_global_load_lds((const __attribute__((address_space(1))) void*)src,
                                       (__attribute__((address_space(3))) void*)(Bs + (w * 2 + i) * 512),
                                       16, 0, 0);
    }
    __syncthreads();
    s16x8 bfr[4];
#pragma unroll
    for (int fn = 0; fn < 4; ++fn) {
      int brow = wc * 64 + fn * 16 + r15;
      bfr[fn] = *(const s16x8*)(Bs + brow * 32 + (hi ^ ((brow >> 1) & 3)) * 8);
    }
#pragma unroll
    for (int fm = 0; fm < 4; ++fm) {
      s16x8 a = *(const s16x8*)(As + (wr * 64 + fm * 16 + r15) * 40 + hi * 8);
#pragma unroll
      for (int fn = 0; fn < 4; ++fn)
        acc[fm][fn] = MFMA16(a, bfr[fn], acc[fm][fn]);
    }
    __syncthreads();
  }
  // epilogue: C = acc + bh   (D layout: col = l&15, row = (l>>4)*4 + j  [m89])
#pragma unroll
  for (int fm = 0; fm < 4; ++fm) {
#pragma unroll
    for (int fn = 0; fn < 4; ++fn) {
      int row = m0 + wr * 64 + fm * 16 + hi * 4;
      int col = n0 + wc * 64 + fn * 16 + r15;
      float bv = bh[col];
#pragma unroll
      for (int j = 0; j < 4; ++j)
        C[(long)(row + j) * 1024 + col] = acc[fm][fn][j] + bv;
    }
  }
}

// ---------------------------------------------------------------------------
// Persistent scan. 256 blocks x 64 threads (ONE wave per block, 1 block/CU).
// Block (bq, cs) owns batch rows [bq*16, bq*16+16) x output cols [cs*16, +16).
// Batch quarters are data-independent -> 4 separate 64-block sync domains.
// Weight slices (3 x 16 cols x 1024, bf16, XOR-granule-swizzled) pinned in LDS.
// Single-wave blocks: no __syncthreads needed anywhere; s_waitcnt is wave-level
// so lane-0's release store orders the whole wave's prior global stores.
// ---------------------------------------------------------------------------
__global__ __launch_bounds__(64) void scan_kernel(
    const float* __restrict__ bmb,
    const u16* __restrict__ Wmh_g, const u16* __restrict__ Whm_g, const u16* __restrict__ Wmm_g,
    u16* m_bf, u16* h_bf, float* out, int* flags) {
  __shared__ __align__(16) u16 Wmh_s[16 * 1024];
  __shared__ __align__(16) u16 Whm_s[16 * 1024];
  __shared__ __align__(16) u16 Wmm_s[16 * 1024];
  const int bid = blockIdx.x;
  const int cs = bid & 63, bq = bid >> 6;              // col-slice, batch-quarter
  const int l = threadIdx.x;
  const int r15 = l & 15, hi = l >> 4;
  int* gflags = flags + bq * 64;                       // own quarter's domain

  // Load W slices into LDS: store src granule (r,g) at (r, g^r). Read applies
  // the same XOR -> per quarter-wave 16 lanes spread over 8 bank-groups (2-way = free).
  for (int g0 = l; g0 < 2048; g0 += 64) {
    int r = g0 >> 7, g = g0 & 127;
    int gs = g ^ r;
    long srcoff = (long)(cs * 16 + r) * 1024 + g * 8;
    *(s16x8*)(Wmh_s + r * 1024 + gs * 8) = *(const s16x8*)(Wmh_g + srcoff);
    *(s16x8*)(Whm_s + r * 1024 + gs * 8) = *(const s16x8*)(Whm_g + srcoff);
    *(s16x8*)(Wmm_s + r * 1024 + gs * 8) = *(const s16x8*)(Wmm_g + srcoff);
  }
  // single wave: ds_write -> ds_read ordered by lgkmcnt, no barrier needed

  const int arow = bq * 16 + r15;                      // A-fragment row (batch)
  const u16* mrow = m_bf + (long)arow * 1024 + hi * 8;
  const u16* hrow = h_bf + (long)arow * 1024 + hi * 8;
  const int orow = bq * 16 + hi * 4;                   // D rows base
  const int ocol = cs * 16 + r15;                      // output column
  const float bmv = bmb[ocol];
  const int wbase = r15 * 1024;                        // LDS row for B-frags

  // xW prefetch for step 0
  float xw[4];
#pragma unroll
  for (int j = 0; j < 4; ++j) xw[j] = out[(long)(orow + j) * 1024 + ocol];

  for (int step = 0; step < 512; ++step) {
    // ---- phase 1: h = tanh(xW_t + m@Wmh^T);  c = m@Wmm^T + bm (regs) ----
    f32x4 acc_h = {0.f, 0.f, 0.f, 0.f};
    f32x4 acc_c = {0.f, 0.f, 0.f, 0.f};
#pragma unroll 8
    for (int kk = 0; kk < 32; ++kk) {
      s16x8 a  = *(const s16x8*)(mrow + kk * 32);
      int gsw  = ((kk * 4 + hi) ^ r15) * 8;
      s16x8 b1 = *(const s16x8*)(Wmh_s + wbase + gsw);
      s16x8 b2 = *(const s16x8*)(Wmm_s + wbase + gsw);
      acc_h = MFMA16(a, b1, acc_h);
      acc_c = MFMA16(a, b2, acc_c);
    }
    const long slot = (long)step * SLOT;
#pragma unroll
    for (int j = 0; j < 4; ++j) {
      h_bf[(long)(orow + j) * 1024 + ocol] = f2bf(tanhf(acc_h[j] + xw[j]));
      acc_c[j] += bmv;
    }
    // ---- barrier B1 (own quarter): h visible to the 64 blocks of bq ----
    {
      const int tgt = 2 * step + 1;
      if (l == 0)
        __hip_atomic_store(gflags + cs, tgt, __ATOMIC_RELEASE, __HIP_MEMORY_SCOPE_AGENT);
      for (;;) {
        int f = __hip_atomic_load(gflags + l, __ATOMIC_RELAXED, __HIP_MEMORY_SCOPE_AGENT);
        if (__all(f >= tgt)) break;
        __builtin_amdgcn_s_sleep(1);
      }
      __threadfence();                                 // acquire side
    }
    // ---- phase 2: m_new = h@Whm^T + c ;  prefetch xW for step+1 ----
    if (step < 511) {
#pragma unroll
      for (int j = 0; j < 4; ++j)
        xw[j] = out[slot + SLOT + (long)(orow + j) * 1024 + ocol];
    }
#pragma unroll 8
    for (int kk = 0; kk < 32; ++kk) {
      s16x8 a = *(const s16x8*)(hrow + kk * 32);
      int gsw = ((kk * 4 + hi) ^ r15) * 8;
      s16x8 b = *(const s16x8*)(Whm_s + wbase + gsw);
      acc_c = MFMA16(a, b, acc_c);
    }
#pragma unroll
    for (int j = 0; j < 4; ++j) {
      float mv = acc_c[j];
      long ro = (long)(orow + j) * 1024 + ocol;
      out[slot + ro] = mv;                       // outs[t] (overwrites consumed xW slot)
      m_bf[ro] = f2bf(mv);                       // state for next step
      if (step == 511) out[FINAL_OFF + ro] = mv; // m_final
    }
    if (step < 511) {
      // ---- barrier B2 (own quarter): m_new visible ----
      const int tgt = 2 * step + 2;
      if (l == 0)
        __hip_atomic_store(gflags + cs, tgt, __ATOMIC_RELEASE, __HIP_MEMORY_SCOPE_AGENT);
      for (;;) {
        int f = __hip_atomic_load(gflags + l, __ATOMIC_RELAXED, __HIP_MEMORY_SCOPE_AGENT);
        if (__all(f >= tgt)) break;
        __builtin_amdgcn_s_sleep(1);
      }
      __threadfence();
    }
  }
}

// ---------------------------------------------------------------------------
extern "C" void kernel_launch(void* const* d_in, const int* in_sizes, int n_in,
                              void* d_out, int out_size, void* d_ws, size_t ws_size,
                              hipStream_t stream) {
  // setup_inputs order: x, m_prev, Wxh, Whm, Wmm, Wmh, bh, bm
  const float* x     = (const float*)d_in[0];
  const float* mprev = (const float*)d_in[1];
  const float* Wxh   = (const float*)d_in[2];
  const float* Whm   = (const float*)d_in[3];
  const float* Wmm   = (const float*)d_in[4];
  const float* Wmh   = (const float*)d_in[5];
  const float* bh    = (const float*)d_in[6];
  const float* bm    = (const float*)d_in[7];
  float* out = (float*)d_out;
  u16* ws = (u16*)d_ws;
  int* flags = (int*)((char*)d_ws + FLAGS_BYTE);

  init_kernel<<<dim3(2048), dim3(256), 0, stream>>>(Wxh, Wmh, Whm, Wmm, mprev, ws, flags);
  gemm_xw<<<dim3(2048), dim3(256), 0, stream>>>(x, ws + OFF_WXH, bh, out);
  scan_kernel<<<dim3(256), dim3(64), 0, stream>>>(bm, ws + OFF_WMH, ws + OFF_WHM,
                                                  ws + OFF_WMM, ws + OFF_M, ws + OFF_H,
                                                  out, flags);
  (void)in_sizes; (void)n_in; (void)out_size; (void)ws_size;
}

// Round 5
// 7232.883 us; speedup vs baseline: 1.8722x; 1.8722x over previous
//
#include <hip/hip_runtime.h>
#include <hip/hip_bf16.h>
#include <math.h>

typedef short s16x8 __attribute__((ext_vector_type(8)));   // 8 bf16 payload (guide-verified frag type)
typedef float f32x4 __attribute__((ext_vector_type(4)));
typedef unsigned short u16;

#define MFMA16(a,b,c) __builtin_amdgcn_mfma_f32_16x16x32_bf16((a),(b),(c),0,0,0)

// Problem dims: IN = HID = MEM = 1024, T = 512, B = 64
static constexpr long SLOT      = 64l * 1024;        // B*MEM elems per timestep
static constexpr long FINAL_OFF = 512l * 64 * 1024;  // offset of m_final in d_out

// ws layout (u16 element offsets)
static constexpr long OFF_WXH = 0;
static constexpr long OFF_WMH = 1048576;
static constexpr long OFF_WHM = 2l * 1048576;
static constexpr long OFF_WMM = 3l * 1048576;
static constexpr long OFF_M   = 4l * 1048576;            // m state, bf16 [64][1024]
static constexpr long OFF_H   = 4l * 1048576 + 65536;    // h buffer, bf16 [64][1024]
static constexpr long FLAGS_BYTE = (4l * 1048576 + 2 * 65536) * 2;  // 256 ints

__device__ __forceinline__ u16 f2bf(float f) {
  union { float f; unsigned u; } v; v.f = f;
  unsigned r = v.u + 0x7FFFu + ((v.u >> 16) & 1u);   // round-to-nearest-even
  return (u16)(r >> 16);
}

// LLC-coherent (cross-XCD) access helpers: sc0 sc1 = bypass L1+L2, read/write
// at the Infinity-Cache coherence point (memory-side, always coherent).
// No buffer_inv / buffer_wbl2 needed anywhere in the step loop.
__device__ __forceinline__ s16x8 llc_load_b128(const u16* p) {
  s16x8 r;
  asm volatile("global_load_dwordx4 %0, %1, off sc0 sc1" : "=&v"(r) : "v"(p));
  return r;
}
__device__ __forceinline__ void llc_store_b16(u16* p, unsigned v) {
  asm volatile("global_store_short %0, %1, off sc0 sc1" :: "v"(p), "v"(v) : "memory");
}

// ---------------------------------------------------------------------------
// init: cast weights + m_prev to bf16 into ws, zero barrier flags
// ---------------------------------------------------------------------------
__global__ void init_kernel(const float* __restrict__ Wxh, const float* __restrict__ Wmh,
                            const float* __restrict__ Whm, const float* __restrict__ Wmm,
                            const float* __restrict__ mprev,
                            u16* __restrict__ ws, int* __restrict__ flags) {
  long tid  = (long)blockIdx.x * blockDim.x + threadIdx.x;
  long nthr = (long)gridDim.x * blockDim.x;
  const long NV = (4l * 1048576 + 65536) / 4;   // float4 groups
  for (long i = tid; i < NV; i += nthr) {
    long e = i * 4;
    const float* src; long rel;
    if      (e < 1048576)      { src = Wxh;   rel = e; }
    else if (e < 2l * 1048576) { src = Wmh;   rel = e - 1048576; }
    else if (e < 3l * 1048576) { src = Whm;   rel = e - 2l * 1048576; }
    else if (e < 4l * 1048576) { src = Wmm;   rel = e - 3l * 1048576; }
    else                       { src = mprev; rel = e - 4l * 1048576; }
    float4 v = *(const float4*)(src + rel);
    ushort4 o;
    o.x = f2bf(v.x); o.y = f2bf(v.y); o.z = f2bf(v.z); o.w = f2bf(v.w);
    *(ushort4*)(ws + e) = o;
  }
  if (tid < 256) flags[tid] = 0;
}

// ---------------------------------------------------------------------------
// xW = x @ Wxh^T + bh  -> written into d_out[0 .. T*B*1024). Slot t is consumed
// by scan phase 1 of step t (same thread) before phase 2 overwrites it with m_t.
// 128x128 tile, BK=32, 4 waves (2x2), bf16 MFMA 16x16x32.   (verified PASS r3)
// ---------------------------------------------------------------------------
__global__ __launch_bounds__(256) void gemm_xw(const float* __restrict__ X,
                                               const u16* __restrict__ Wb,
                                               const float* __restrict__ bh,
                                               float* __restrict__ C) {
  __shared__ __align__(16) u16 As[128 * 40];   // padded stride 40 (2-way max on reads)
  __shared__ __align__(16) u16 Bs[128 * 32];   // linear (global_load_lds destination)
  const int m0 = (blockIdx.x >> 3) * 128;
  const int n0 = (blockIdx.x & 7) * 128;
  const int t = threadIdx.x, l = t & 63, w = t >> 6;
  const int wr = w >> 1, wc = w & 1;
  const int r15 = l & 15, hi = l >> 4;
  f32x4 acc[4][4] = {};

  for (int k0 = 0; k0 < 1024; k0 += 32) {
#pragma unroll
    for (int r = 0; r < 4; ++r) {
      int idx = r * 256 + t;
      int row = idx >> 3, c4 = idx & 7;
      float4 v = *(const float4*)(X + (long)(m0 + row) * 1024 + k0 + c4 * 4);
      ushort4 o;
      o.x = f2bf(v.x); o.y = f2bf(v.y); o.z = f2bf(v.z); o.w = f2bf(v.w);
      *(ushort4*)(As + row * 40 + c4 * 4) = o;
    }
#pragma unroll
    for (int i = 0; i < 2; ++i) {
      int g = (w * 2 + i) * 64 + l;
      int row = g >> 2;
      int kgs = (g & 3) ^ ((row >> 1) & 3);
      const u16* src = Wb + (long)(n0 + row) * 1024 + k0 + kgs * 8;
      __builtin_amdgcn_global_load_lds((const __attribute__((address_space(1))) void*)src,
                                       (__attribute__((address_space(3))) void*)(Bs + (w * 2 + i) * 512),
                                       16, 0, 0);
    }
    __syncthreads();
    s16x8 bfr[4];
#pragma unroll
    for (int fn = 0; fn < 4; ++fn) {
      int brow = wc * 64 + fn * 16 + r15;
      bfr[fn] = *(const s16x8*)(Bs + brow * 32 + (hi ^ ((brow >> 1) & 3)) * 8);
    }
#pragma unroll
    for (int fm = 0; fm < 4; ++fm) {
      s16x8 a = *(const s16x8*)(As + (wr * 64 + fm * 16 + r15) * 40 + hi * 8);
#pragma unroll
      for (int fn = 0; fn < 4; ++fn)
        acc[fm][fn] = MFMA16(a, bfr[fn], acc[fm][fn]);
    }
    __syncthreads();
  }
#pragma unroll
  for (int fm = 0; fm < 4; ++fm) {
#pragma unroll
    for (int fn = 0; fn < 4; ++fn) {
      int row = m0 + wr * 64 + fm * 16 + hi * 4;
      int col = n0 + wc * 64 + fn * 16 + r15;
      float bv = bh[col];
#pragma unroll
      for (int j = 0; j < 4; ++j)
        C[(long)(row + j) * 1024 + col] = acc[fm][fn][j] + bv;
    }
  }
}

// ---------------------------------------------------------------------------
// Persistent scan. 256 blocks x 64 threads (ONE wave per block, 1 block/CU).
// Block (bq, cs) owns batch rows [bq*16, +16) x output cols [cs*16, +16).
// Batch quarters are data-independent -> 4 separate 64-block sync domains.
// Cross-XCD state (m_bf, h_bf) moves through the LLC via sc0sc1 write-through
// stores + bypass loads. Barrier = vmcnt(0) drain + RELAXED agent flag store +
// relaxed poll: ZERO cache-maintenance ops (wbl2/inv) in the step loop
// (r3 post-mortem: agent release/acquire fences 4x/step = 95% of 13.4 ms).
// ---------------------------------------------------------------------------
__global__ __launch_bounds__(64) void scan_kernel(
    const float* __restrict__ bmb,
    const u16* __restrict__ Wmh_g, const u16* __restrict__ Whm_g, const u16* __restrict__ Wmm_g,
    u16* m_bf, u16* h_bf, float* out, int* flags) {
  __shared__ __align__(16) u16 Wmh_s[16 * 1024];
  __shared__ __align__(16) u16 Whm_s[16 * 1024];
  __shared__ __align__(16) u16 Wmm_s[16 * 1024];
  const int bid = blockIdx.x;
  const int cs = bid & 63, bq = bid >> 6;              // col-slice, batch-quarter
  const int l = threadIdx.x;
  const int r15 = l & 15, hi = l >> 4;
  int* gflags = flags + bq * 64;                       // own quarter's domain

  // Pin W slices in LDS: store src granule (r,g) at (r, g^r); read applies the
  // same XOR -> 16-lane column reads spread over 8 bank-groups (2-way = free).
  for (int g0 = l; g0 < 2048; g0 += 64) {
    int r = g0 >> 7, g = g0 & 127;
    int gs = g ^ r;
    long srcoff = (long)(cs * 16 + r) * 1024 + g * 8;
    *(s16x8*)(Wmh_s + r * 1024 + gs * 8) = *(const s16x8*)(Wmh_g + srcoff);
    *(s16x8*)(Whm_s + r * 1024 + gs * 8) = *(const s16x8*)(Whm_g + srcoff);
    *(s16x8*)(Wmm_s + r * 1024 + gs * 8) = *(const s16x8*)(Wmm_g + srcoff);
  }
  // single wave: ds_write -> ds_read ordered by lgkmcnt, no barrier needed

  const int arow = bq * 16 + r15;                      // A-fragment row (batch)
  const u16* mrow = m_bf + (long)arow * 1024 + hi * 8;
  const u16* hrow = h_bf + (long)arow * 1024 + hi * 8;
  const int orow = bq * 16 + hi * 4;                   // D rows base
  const int ocol = cs * 16 + r15;                      // output column
  const float bmv = bmb[ocol];
  const int wbase = r15 * 1024;                        // LDS row for B-frags

  // xW prefetch for step 0 (plain cached: lines are thread-private in the scan)
  float xw[4];
#pragma unroll
  for (int j = 0; j < 4; ++j) xw[j] = out[(long)(orow + j) * 1024 + ocol];

  for (int step = 0; step < 512; ++step) {
    // ---- phase 1: h = tanh(xW_t + m@Wmh^T);  c = m@Wmm^T + bm (regs) ----
    s16x8 mf[32];
#pragma unroll
    for (int kk = 0; kk < 32; ++kk) mf[kk] = llc_load_b128(mrow + kk * 32);
    asm volatile("s_waitcnt vmcnt(0)" ::: "memory");
    __builtin_amdgcn_sched_barrier(0);

    f32x4 acc_h = {0.f, 0.f, 0.f, 0.f};
    f32x4 acc_c = {0.f, 0.f, 0.f, 0.f};
#pragma unroll
    for (int kk = 0; kk < 32; ++kk) {
      int gsw  = ((kk * 4 + hi) ^ r15) * 8;
      s16x8 b1 = *(const s16x8*)(Wmh_s + wbase + gsw);
      s16x8 b2 = *(const s16x8*)(Wmm_s + wbase + gsw);
      acc_h = MFMA16(mf[kk], b1, acc_h);
      acc_c = MFMA16(mf[kk], b2, acc_c);
    }
    const long slot = (long)step * SLOT;
#pragma unroll
    for (int j = 0; j < 4; ++j) {
      llc_store_b16(h_bf + (long)(orow + j) * 1024 + ocol, f2bf(tanhf(acc_h[j] + xw[j])));
      acc_c[j] += bmv;
    }
    // ---- barrier B1 (own quarter): h committed to LLC, then publish flag ----
    {
      const int tgt = 2 * step + 1;
      asm volatile("s_waitcnt vmcnt(0)" ::: "memory");        // h stores at LLC
      if (l == 0)
        __hip_atomic_store(gflags + cs, tgt, __ATOMIC_RELAXED, __HIP_MEMORY_SCOPE_AGENT);
      // xW prefetch for step+1 rides under the barrier wait
      if (step < 511) {
#pragma unroll
        for (int j = 0; j < 4; ++j)
          xw[j] = out[slot + SLOT + (long)(orow + j) * 1024 + ocol];
      }
      for (;;) {
        int f = __hip_atomic_load(gflags + l, __ATOMIC_RELAXED, __HIP_MEMORY_SCOPE_AGENT);
        if (__all(f >= tgt)) break;
        __builtin_amdgcn_s_sleep(1);
      }
      __builtin_amdgcn_sched_barrier(0);
      asm volatile("" ::: "memory");
    }
    // ---- phase 2: m_new = h@Whm^T + c ----
    s16x8 hf[32];
#pragma unroll
    for (int kk = 0; kk < 32; ++kk) hf[kk] = llc_load_b128(hrow + kk * 32);
    asm volatile("s_waitcnt vmcnt(0)" ::: "memory");
    __builtin_amdgcn_sched_barrier(0);

#pragma unroll
    for (int kk = 0; kk < 32; ++kk) {
      int gsw = ((kk * 4 + hi) ^ r15) * 8;
      s16x8 b = *(const s16x8*)(Whm_s + wbase + gsw);
      acc_c = MFMA16(hf[kk], b, acc_c);
    }
#pragma unroll
    for (int j = 0; j < 4; ++j) {
      float mv = acc_c[j];
      long ro = (long)(orow + j) * 1024 + ocol;
      out[slot + ro] = mv;                             // outs[t] (plain cached)
      llc_store_b16(m_bf + ro, f2bf(mv));              // state for next step
      if (step == 511) out[FINAL_OFF + ro] = mv;       // m_final
    }
    if (step < 511) {
      // ---- barrier B2 (own quarter): m_new committed to LLC ----
      const int tgt = 2 * step + 2;
      asm volatile("s_waitcnt vmcnt(0)" ::: "memory");        // m stores at LLC
      if (l == 0)
        __hip_atomic_store(gflags + cs, tgt, __ATOMIC_RELAXED, __HIP_MEMORY_SCOPE_AGENT);
      for (;;) {
        int f = __hip_atomic_load(gflags + l, __ATOMIC_RELAXED, __HIP_MEMORY_SCOPE_AGENT);
        if (__all(f >= tgt)) break;
        __builtin_amdgcn_s_sleep(1);
      }
      __builtin_amdgcn_sched_barrier(0);
      asm volatile("" ::: "memory");
    }
  }
}

// ---------------------------------------------------------------------------
extern "C" void kernel_launch(void* const* d_in, const int* in_sizes, int n_in,
                              void* d_out, int out_size, void* d_ws, size_t ws_size,
                              hipStream_t stream) {
  // setup_inputs order: x, m_prev, Wxh, Whm, Wmm, Wmh, bh, bm
  const float* x     = (const float*)d_in[0];
  const float* mprev = (const float*)d_in[1];
  const float* Wxh   = (const float*)d_in[2];
  const float* Whm   = (const float*)d_in[3];
  const float* Wmm   = (const float*)d_in[4];
  const float* Wmh   = (const float*)d_in[5];
  const float* bh    = (const float*)d_in[6];
  const float* bm    = (const float*)d_in[7];
  float* out = (float*)d_out;
  u16* ws = (u16*)d_ws;
  int* flags = (int*)((char*)d_ws + FLAGS_BYTE);

  init_kernel<<<dim3(2048), dim3(256), 0, stream>>>(Wxh, Wmh, Whm, Wmm, mprev, ws, flags);
  gemm_xw<<<dim3(2048), dim3(256), 0, stream>>>(x, ws + OFF_WXH, bh, out);
  scan_kernel<<<dim3(256), dim3(64), 0, stream>>>(bm, ws + OFF_WMH, ws + OFF_WHM,
                                                  ws + OFF_WMM, ws + OFF_M, ws + OFF_H,
                                                  out, flags);
  (void)in_sizes; (void)n_in; (void)out_size; (void)ws_size;
}

// Round 6
// 5771.177 us; speedup vs baseline: 2.3464x; 1.2533x over previous
//
#include <hip/hip_runtime.h>
#include <hip/hip_bf16.h>
#include <math.h>

typedef short s16x8 __attribute__((ext_vector_type(8)));   // 8 bf16 payload (guide-verified frag type)
typedef float f32x4 __attribute__((ext_vector_type(4)));
typedef unsigned short u16;

#define MFMA16(a,b,c) __builtin_amdgcn_mfma_f32_16x16x32_bf16((a),(b),(c),0,0,0)

// Problem dims: IN = HID = MEM = 1024, T = 512, B = 64
static constexpr long SLOT      = 64l * 1024;        // B*MEM elems per timestep
static constexpr long FINAL_OFF = 512l * 64 * 1024;  // offset of m_final in d_out

// ws layout (u16 element offsets)
static constexpr long OFF_WXH = 0;
static constexpr long OFF_WMH = 1048576;
static constexpr long OFF_WHM = 2l * 1048576;
static constexpr long OFF_WMM = 3l * 1048576;
static constexpr long OFF_M   = 4l * 1048576;            // m state, bf16 [64][1024]
static constexpr long OFF_H   = 4l * 1048576 + 65536;    // h buffer, bf16 [64][1024]
static constexpr long FLAGS_BYTE = (4l * 1048576 + 2 * 65536) * 2;  // 256 ints

__device__ __forceinline__ u16 f2bf(float f) {
  union { float f; unsigned u; } v; v.f = f;
  unsigned r = v.u + 0x7FFFu + ((v.u >> 16) & 1u);   // round-to-nearest-even
  return (u16)(r >> 16);
}

// LLC-coherent (cross-XCD) access helpers: sc0 sc1 = bypass L1+L2, read/write
// at the Infinity-Cache coherence point (memory-side, always coherent).
// No buffer_inv / buffer_wbl2 needed anywhere in the step loop.
__device__ __forceinline__ s16x8 llc_load_b128(const u16* p) {
  s16x8 r;
  asm volatile("global_load_dwordx4 %0, %1, off sc0 sc1" : "=&v"(r) : "v"(p));
  return r;
}
__device__ __forceinline__ void llc_store_b16(u16* p, unsigned v) {
  asm volatile("global_store_short %0, %1, off sc0 sc1" :: "v"(p), "v"(v) : "memory");
}

// ---------------------------------------------------------------------------
// init: cast weights + m_prev to bf16 into ws, zero barrier flags
// ---------------------------------------------------------------------------
__global__ void init_kernel(const float* __restrict__ Wxh, const float* __restrict__ Wmh,
                            const float* __restrict__ Whm, const float* __restrict__ Wmm,
                            const float* __restrict__ mprev,
                            u16* __restrict__ ws, int* __restrict__ flags) {
  long tid  = (long)blockIdx.x * blockDim.x + threadIdx.x;
  long nthr = (long)gridDim.x * blockDim.x;
  const long NV = (4l * 1048576 + 65536) / 4;   // float4 groups
  for (long i = tid; i < NV; i += nthr) {
    long e = i * 4;
    const float* src; long rel;
    if      (e < 1048576)      { src = Wxh;   rel = e; }
    else if (e < 2l * 1048576) { src = Wmh;   rel = e - 1048576; }
    else if (e < 3l * 1048576) { src = Whm;   rel = e - 2l * 1048576; }
    else if (e < 4l * 1048576) { src = Wmm;   rel = e - 3l * 1048576; }
    else                       { src = mprev; rel = e - 4l * 1048576; }
    float4 v = *(const float4*)(src + rel);
    ushort4 o;
    o.x = f2bf(v.x); o.y = f2bf(v.y); o.z = f2bf(v.z); o.w = f2bf(v.w);
    *(ushort4*)(ws + e) = o;
  }
  if (tid < 256) flags[tid] = 0;
}

// ---------------------------------------------------------------------------
// xW = x @ Wxh^T + bh  -> written into d_out[0 .. T*B*1024). Slot t is consumed
// by scan phase 1 of step t (same thread) before phase 2 overwrites it with m_t.
// 128x128 tile, BK=32, 4 waves (2x2), bf16 MFMA 16x16x32.   (verified PASS r3/r5)
// ---------------------------------------------------------------------------
__global__ __launch_bounds__(256) void gemm_xw(const float* __restrict__ X,
                                               const u16* __restrict__ Wb,
                                               const float* __restrict__ bh,
                                               float* __restrict__ C) {
  __shared__ __align__(16) u16 As[128 * 40];   // padded stride 40 (2-way max on reads)
  __shared__ __align__(16) u16 Bs[128 * 32];   // linear (global_load_lds destination)
  const int m0 = (blockIdx.x >> 3) * 128;
  const int n0 = (blockIdx.x & 7) * 128;
  const int t = threadIdx.x, l = t & 63, w = t >> 6;
  const int wr = w >> 1, wc = w & 1;
  const int r15 = l & 15, hi = l >> 4;
  f32x4 acc[4][4] = {};

  for (int k0 = 0; k0 < 1024; k0 += 32) {
#pragma unroll
    for (int r = 0; r < 4; ++r) {
      int idx = r * 256 + t;
      int row = idx >> 3, c4 = idx & 7;
      float4 v = *(const float4*)(X + (long)(m0 + row) * 1024 + k0 + c4 * 4);
      ushort4 o;
      o.x = f2bf(v.x); o.y = f2bf(v.y); o.z = f2bf(v.z); o.w = f2bf(v.w);
      *(ushort4*)(As + row * 40 + c4 * 4) = o;
    }
#pragma unroll
    for (int i = 0; i < 2; ++i) {
      int g = (w * 2 + i) * 64 + l;
      int row = g >> 2;
      int kgs = (g & 3) ^ ((row >> 1) & 3);
      const u16* src = Wb + (long)(n0 + row) * 1024 + k0 + kgs * 8;
      __builtin_amdgcn_global_load_lds((const __attribute__((address_space(1))) void*)src,
                                       (__attribute__((address_space(3))) void*)(Bs + (w * 2 + i) * 512),
                                       16, 0, 0);
    }
    __syncthreads();
    s16x8 bfr[4];
#pragma unroll
    for (int fn = 0; fn < 4; ++fn) {
      int brow = wc * 64 + fn * 16 + r15;
      bfr[fn] = *(const s16x8*)(Bs + brow * 32 + (hi ^ ((brow >> 1) & 3)) * 8);
    }
#pragma unroll
    for (int fm = 0; fm < 4; ++fm) {
      s16x8 a = *(const s16x8*)(As + (wr * 64 + fm * 16 + r15) * 40 + hi * 8);
#pragma unroll
      for (int fn = 0; fn < 4; ++fn)
        acc[fm][fn] = MFMA16(a, bfr[fn], acc[fm][fn]);
    }
    __syncthreads();
  }
#pragma unroll
  for (int fm = 0; fm < 4; ++fm) {
#pragma unroll
    for (int fn = 0; fn < 4; ++fn) {
      int row = m0 + wr * 64 + fm * 16 + hi * 4;
      int col = n0 + wc * 64 + fn * 16 + r15;
      float bv = bh[col];
#pragma unroll
      for (int j = 0; j < 4; ++j)
        C[(long)(row + j) * 1024 + col] = acc[fm][fn][j] + bv;
    }
  }
}

// ---------------------------------------------------------------------------
// Persistent scan. 256 blocks x 64 threads (ONE wave per block, 1 block/CU).
// Block (bq, cs) owns batch rows [bq*16, +16) x output cols [cs*16, +16).
// Batch quarters are data-independent -> 4 separate 64-block sync domains.
// State (m,h) moves through the LLC via sc0sc1 stores/loads (r5: PASS, -48%).
// r5 post-mortem: ~5.6us/barrier remained; suspect = lazy write-combine flush
// of the plain sc1 flag store (producer never vmcnt-waits on it before its
// own poll). Fix: publish via far-atomic global_atomic_add (executes at LLC,
// immediate visibility) + move the Wmm GEMM and xW prefetch into the B1 wait
// window (off the critical path).
// ---------------------------------------------------------------------------
__global__ __launch_bounds__(64) void scan_kernel(
    const float* __restrict__ bmb,
    const u16* __restrict__ Wmh_g, const u16* __restrict__ Whm_g, const u16* __restrict__ Wmm_g,
    u16* m_bf, u16* h_bf, float* out, int* flags) {
  __shared__ __align__(16) u16 Wmh_s[16 * 1024];
  __shared__ __align__(16) u16 Whm_s[16 * 1024];
  __shared__ __align__(16) u16 Wmm_s[16 * 1024];
  const int bid = blockIdx.x;
  const int cs = bid & 63, bq = bid >> 6;              // col-slice, batch-quarter
  const int l = threadIdx.x;
  const int r15 = l & 15, hi = l >> 4;
  int* gflags = flags + bq * 64;                       // own quarter's domain

  // Pin W slices in LDS: store src granule (r,g) at (r, g^r); read applies the
  // same XOR -> 16-lane column reads spread over 8 bank-groups (2-way = free).
  for (int g0 = l; g0 < 2048; g0 += 64) {
    int r = g0 >> 7, g = g0 & 127;
    int gs = g ^ r;
    long srcoff = (long)(cs * 16 + r) * 1024 + g * 8;
    *(s16x8*)(Wmh_s + r * 1024 + gs * 8) = *(const s16x8*)(Wmh_g + srcoff);
    *(s16x8*)(Whm_s + r * 1024 + gs * 8) = *(const s16x8*)(Whm_g + srcoff);
    *(s16x8*)(Wmm_s + r * 1024 + gs * 8) = *(const s16x8*)(Wmm_g + srcoff);
  }
  // single wave: ds_write -> ds_read ordered by lgkmcnt, no barrier needed

  const int arow = bq * 16 + r15;                      // A-fragment row (batch)
  const u16* mrow = m_bf + (long)arow * 1024 + hi * 8;
  const u16* hrow = h_bf + (long)arow * 1024 + hi * 8;
  const int orow = bq * 16 + hi * 4;                   // D rows base
  const int ocol = cs * 16 + r15;                      // output column
  const float bmv = bmb[ocol];
  const int wbase = r15 * 1024;                        // LDS row for B-frags

  // xW prefetch for step 0 (plain cached: lines are thread-private in the scan)
  float xw[4];
#pragma unroll
  for (int j = 0; j < 4; ++j) xw[j] = out[(long)(orow + j) * 1024 + ocol];

  for (int step = 0; step < 512; ++step) {
    const long slot = (long)step * SLOT;
    // ---- phase 1a: load m; acc_h = m@Wmh^T ----
    s16x8 mf[32];
#pragma unroll
    for (int kk = 0; kk < 32; ++kk) mf[kk] = llc_load_b128(mrow + kk * 32);
    asm volatile("s_waitcnt vmcnt(0)" ::: "memory");
    __builtin_amdgcn_sched_barrier(0);

    f32x4 acc_h = {0.f, 0.f, 0.f, 0.f};
#pragma unroll
    for (int kk = 0; kk < 32; ++kk) {
      int gsw = ((kk * 4 + hi) ^ r15) * 8;
      acc_h = MFMA16(mf[kk], *(const s16x8*)(Wmh_s + wbase + gsw), acc_h);
    }
    // h = tanh(xW_t + acc_h) -> LLC, then publish B1 ASAP (far atomic)
#pragma unroll
    for (int j = 0; j < 4; ++j)
      llc_store_b16(h_bf + (long)(orow + j) * 1024 + ocol, f2bf(tanhf(acc_h[j] + xw[j])));
    asm volatile("s_waitcnt vmcnt(0)" ::: "memory");        // h committed at LLC
    if (l == 0)
      (void)__hip_atomic_fetch_add(gflags + cs, 1, __ATOMIC_RELAXED, __HIP_MEMORY_SCOPE_AGENT);
    __builtin_amdgcn_sched_barrier(0);

    // ---- B1 wait window: acc_c = m@Wmm^T + bm, and xW prefetch for t+1 ----
    f32x4 acc_c = {0.f, 0.f, 0.f, 0.f};
#pragma unroll
    for (int kk = 0; kk < 32; ++kk) {
      int gsw = ((kk * 4 + hi) ^ r15) * 8;
      acc_c = MFMA16(mf[kk], *(const s16x8*)(Wmm_s + wbase + gsw), acc_c);
    }
#pragma unroll
    for (int j = 0; j < 4; ++j) acc_c[j] += bmv;
    if (step < 511) {
#pragma unroll
      for (int j = 0; j < 4; ++j)
        xw[j] = out[slot + SLOT + (long)(orow + j) * 1024 + ocol];
    }
    // ---- B1 poll: all h of own quarter at LLC ----
    {
      const int tgt = 2 * step + 1;
      for (;;) {
        int f = __hip_atomic_load(gflags + l, __ATOMIC_RELAXED, __HIP_MEMORY_SCOPE_AGENT);
        if (__all(f >= tgt)) break;
        __builtin_amdgcn_s_sleep(1);
      }
      __builtin_amdgcn_sched_barrier(0);
      asm volatile("" ::: "memory");
    }
    // ---- phase 2: m_new = h@Whm^T + acc_c ----
    s16x8 hf[32];
#pragma unroll
    for (int kk = 0; kk < 32; ++kk) hf[kk] = llc_load_b128(hrow + kk * 32);
    asm volatile("s_waitcnt vmcnt(0)" ::: "memory");
    __builtin_amdgcn_sched_barrier(0);

#pragma unroll
    for (int kk = 0; kk < 32; ++kk) {
      int gsw = ((kk * 4 + hi) ^ r15) * 8;
      acc_c = MFMA16(hf[kk], *(const s16x8*)(Whm_s + wbase + gsw), acc_c);
    }
#pragma unroll
    for (int j = 0; j < 4; ++j) {
      float mv = acc_c[j];
      long ro = (long)(orow + j) * 1024 + ocol;
      out[slot + ro] = mv;                             // outs[t] (plain cached)
      llc_store_b16(m_bf + ro, f2bf(mv));              // state for next step
      if (step == 511) out[FINAL_OFF + ro] = mv;       // m_final
    }
    if (step < 511) {
      // ---- B2: m committed at LLC, far-atomic publish, poll ----
      const int tgt = 2 * step + 2;
      asm volatile("s_waitcnt vmcnt(0)" ::: "memory");
      if (l == 0)
        (void)__hip_atomic_fetch_add(gflags + cs, 1, __ATOMIC_RELAXED, __HIP_MEMORY_SCOPE_AGENT);
      for (;;) {
        int f = __hip_atomic_load(gflags + l, __ATOMIC_RELAXED, __HIP_MEMORY_SCOPE_AGENT);
        if (__all(f >= tgt)) break;
        __builtin_amdgcn_s_sleep(1);
      }
      __builtin_amdgcn_sched_barrier(0);
      asm volatile("" ::: "memory");
    }
  }
}

// ---------------------------------------------------------------------------
extern "C" void kernel_launch(void* const* d_in, const int* in_sizes, int n_in,
                              void* d_out, int out_size, void* d_ws, size_t ws_size,
                              hipStream_t stream) {
  // setup_inputs order: x, m_prev, Wxh, Whm, Wmm, Wmh, bh, bm
  const float* x     = (const float*)d_in[0];
  const float* mprev = (const float*)d_in[1];
  const float* Wxh   = (const float*)d_in[2];
  const float* Whm   = (const float*)d_in[3];
  const float* Wmm   = (const float*)d_in[4];
  const float* Wmh   = (const float*)d_in[5];
  const float* bh    = (const float*)d_in[6];
  const float* bm    = (const float*)d_in[7];
  float* out = (float*)d_out;
  u16* ws = (u16*)d_ws;
  int* flags = (int*)((char*)d_ws + FLAGS_BYTE);

  init_kernel<<<dim3(2048), dim3(256), 0, stream>>>(Wxh, Wmh, Whm, Wmm, mprev, ws, flags);
  gemm_xw<<<dim3(2048), dim3(256), 0, stream>>>(x, ws + OFF_WXH, bh, out);
  scan_kernel<<<dim3(256), dim3(64), 0, stream>>>(bm, ws + OFF_WMH, ws + OFF_WHM,
                                                  ws + OFF_WMM, ws + OFF_M, ws + OFF_H,
                                                  out, flags);
  (void)in_sizes; (void)n_in; (void)out_size; (void)ws_size;
}